// Round 1
// baseline (694.844 us; speedup 1.0000x reference)
//
#include <hip/hip_runtime.h>
#include <stdint.h>

#define B_    32
#define H_    8
#define KLEN_ 8192
#define D_    64
#define SPLIT 8                              // blocks per (b,h)
#define ROWS_PER_BLOCK (KLEN_ / SPLIT)       // 1024
#define WAVES 4
#define ITERS (ROWS_PER_BLOCK / (WAVES * 16)) // 16

typedef __attribute__((ext_vector_type(8))) short short8;   // 8 bf16 in 4 VGPRs
typedef __attribute__((ext_vector_type(4))) float float4v;

static __device__ inline unsigned short f2bf(float f) {
    // round-to-nearest-even f32 -> bf16
    uint32_t u = __builtin_bit_cast(uint32_t, f);
    u += 0x7fffu + ((u >> 16) & 1u);
    return (unsigned short)(u >> 16);
}

__global__ __launch_bounds__(256) void nais_score_kernel(
    const float* __restrict__ Q,    // [B,H,1,D]
    const float* __restrict__ K,    // [B,H,KLEN,D]
    const float* __restrict__ Wc,   // [H,2D,D]
    const float* __restrict__ Wo,   // [H,D,1]
    const float* __restrict__ bias, // [H,1,D]
    float* __restrict__ out)        // [B,H,KLEN]
{
    const int blk   = blockIdx.x;
    const int bh    = blk / SPLIT;
    const int split = blk % SPLIT;
    const int h     = bh % H_;
    const int tid   = threadIdx.x;
    const int lane  = tid & 63;
    const int wave  = tid >> 6;
    const int c     = lane & 15;   // A-row / C-col index within 16-tile
    const int q     = lane >> 4;   // quad

    __shared__ float s_qb[D_];
    __shared__ float s_wo[D_];

    // ---- q_proj[d] = bias[h,d] + sum_e Q[b,h,e] * Wc[h][e][d]   (fp32, exact) ----
    if (tid < D_) {
        const float* qv = Q + (size_t)bh * D_;
        const float* wq = Wc + (size_t)h * (2 * D_ * D_);
        float acc = bias[h * D_ + tid];
        #pragma unroll 8
        for (int e = 0; e < D_; ++e)
            acc += qv[e] * wq[e * D_ + tid];
        s_qb[tid] = acc;
        s_wo[tid] = Wo[h * D_ + tid];
    }
    __syncthreads();

    // ---- persistent B fragments: Wk[e][d] = Wc[h][64+e][d], bf16 ----
    // B layout for 16x16x32: lane holds B[k = quad*8+j][n = lane&15]
    const float* wk = Wc + (size_t)h * (2 * D_ * D_) + D_ * D_;
    short8 bfrag[4][2];
    #pragma unroll
    for (int t = 0; t < 4; ++t) {
        const int d = t * 16 + c;
        #pragma unroll
        for (int half = 0; half < 2; ++half) {
            short8 f;
            #pragma unroll
            for (int j = 0; j < 8; ++j) {
                const int e = half * 32 + q * 8 + j;
                f[j] = (short)f2bf(wk[e * D_ + d]);
            }
            bfrag[t][half] = f;
        }
    }

    float qbl[4], wol[4];
    #pragma unroll
    for (int t = 0; t < 4; ++t) {
        qbl[t] = s_qb[t * 16 + c];
        wol[t] = s_wo[t * 16 + c];
    }

    const float* Kb = K + (size_t)bh * KLEN_ * D_ + (size_t)split * ROWS_PER_BLOCK * D_;
    float*       ob = out + (size_t)bh * KLEN_ + (size_t)split * ROWS_PER_BLOCK;

    for (int it = 0; it < ITERS; ++it) {
        const int krow = (it * WAVES + wave) * 16;
        // A fragments: lane holds K[krow + c][e], e = half*32 + q*8 + j
        const float* arow = Kb + (size_t)(krow + c) * D_ + q * 8;
        float4v a0lo = *(const float4v*)(arow);
        float4v a0hi = *(const float4v*)(arow + 4);
        float4v a1lo = *(const float4v*)(arow + 32);
        float4v a1hi = *(const float4v*)(arow + 36);
        short8 af0, af1;
        #pragma unroll
        for (int j = 0; j < 4; ++j) {
            af0[j]     = (short)f2bf(a0lo[j]);
            af0[j + 4] = (short)f2bf(a0hi[j]);
            af1[j]     = (short)f2bf(a1lo[j]);
            af1[j + 4] = (short)f2bf(a1hi[j]);
        }

        // hidden tile -> relu -> dot with Wo, accumulated per-lane over d-tiles
        float4v pr = {0.f, 0.f, 0.f, 0.f};
        #pragma unroll
        for (int t = 0; t < 4; ++t) {
            float4v acc = {0.f, 0.f, 0.f, 0.f};
            acc = __builtin_amdgcn_mfma_f32_16x16x32_bf16(af0, bfrag[t][0], acc, 0, 0, 0);
            acc = __builtin_amdgcn_mfma_f32_16x16x32_bf16(af1, bfrag[t][1], acc, 0, 0, 0);
            #pragma unroll
            for (int r = 0; r < 4; ++r) {
                float hv = acc[r] + qbl[t];   // C/D: col=lane&15, row=q*4+r
                hv = fmaxf(hv, 0.f);
                pr[r] += hv * wol[t];
            }
        }

        // reduce over the 16 d-columns (lanes sharing a quad), then store
        #pragma unroll
        for (int r = 0; r < 4; ++r) {
            float v = pr[r];
            v += __shfl_xor(v, 1);
            v += __shfl_xor(v, 2);
            v += __shfl_xor(v, 4);
            v += __shfl_xor(v, 8);
            if (c == r) ob[krow + q * 4 + r] = v;
        }
    }
}

extern "C" void kernel_launch(void* const* d_in, const int* in_sizes, int n_in,
                              void* d_out, int out_size, void* d_ws, size_t ws_size,
                              hipStream_t stream) {
    const float* Q    = (const float*)d_in[0];
    const float* K    = (const float*)d_in[1];
    const float* Wc   = (const float*)d_in[2];
    const float* Wo   = (const float*)d_in[3];
    const float* bias = (const float*)d_in[4];
    float* out = (float*)d_out;

    dim3 grid(B_ * H_ * SPLIT);  // 2048 blocks
    dim3 block(256);
    nais_score_kernel<<<grid, block, 0, stream>>>(Q, K, Wc, Wo, bias, out);
}

// Round 2
// 692.732 us; speedup vs baseline: 1.0030x; 1.0030x over previous
//
#include <hip/hip_runtime.h>
#include <stdint.h>

#define B_    32
#define H_    8
#define KLEN_ 8192
#define D_    64
#define SPLIT 16                             // blocks per (b,h)
#define ROWS_PER_BLOCK (KLEN_ / SPLIT)       // 512
#define WAVES 4
#define TILES (ROWS_PER_BLOCK / (WAVES * 16)) // 8 tiles of 16 rows per wave

#define LDS_ROW 144   // bytes per bf16 row in LDS: 128 data + 16 pad (kills bank conflicts)

typedef __attribute__((ext_vector_type(8))) short short8;       // 8 bf16 (4 VGPRs)
typedef __attribute__((ext_vector_type(4))) float float4v;
typedef __attribute__((ext_vector_type(4))) unsigned int uint4v;
typedef __attribute__((ext_vector_type(2))) unsigned int uint2v;

// pack two f32 -> bf16x2 dword (round-half-up; 2 adds + 1 v_perm_b32)
static __device__ inline unsigned int pack_bf16(float x0, float x1) {
    unsigned int a = __builtin_bit_cast(unsigned int, x0) + 0x8000u;
    unsigned int b = __builtin_bit_cast(unsigned int, x1) + 0x8000u;
    // D = [a.b2, a.b3, b.b2, b.b3]  -> low16 = bf16(x0), high16 = bf16(x1)
    return __builtin_amdgcn_perm(b, a, 0x07060302u);
}

__global__ __launch_bounds__(256) void nais_score_kernel(
    const float* __restrict__ Q,    // [B,H,1,D]
    const float* __restrict__ K,    // [B,H,KLEN,D]
    const float* __restrict__ Wc,   // [H,2D,D]
    const float* __restrict__ Wo,   // [H,D,1]
    const float* __restrict__ bias, // [H,1,D]
    float* __restrict__ out)        // [B,H,KLEN]
{
    const int blk   = blockIdx.x;
    const int bh    = blk / SPLIT;
    const int split = blk % SPLIT;
    const int h     = bh % H_;
    const int tid   = threadIdx.x;
    const int lane  = tid & 63;
    const int wave  = tid >> 6;
    const int c     = lane & 15;   // A-row / C-col / write-col index
    const int q     = lane >> 4;   // quad

    __shared__ float s_qb[D_];
    __shared__ float s_wo[D_];
    // wave-private bf16 tiles: 16 rows x 144 B each
    __shared__ unsigned char s_tile[WAVES][16 * LDS_ROW] __attribute__((aligned(16)));

    // ---- q_proj[d] = bias[h,d] + sum_e Q[b,h,e] * Wc[h][e][d]  (fp32, exact) ----
    if (tid < D_) {
        const float* qv = Q + (size_t)bh * D_;
        const float* wq = Wc + (size_t)h * (2 * D_ * D_);
        float acc = bias[h * D_ + tid];
        #pragma unroll 8
        for (int e = 0; e < D_; ++e)
            acc += qv[e] * wq[e * D_ + tid];
        s_qb[tid] = acc;
        s_wo[tid] = Wo[h * D_ + tid];
    }
    __syncthreads();

    // ---- persistent B fragments: Wk[e][d] = Wc[h][64+e][d], bf16 ----
    // B layout 16x16x32: lane holds B[k = q*8+j][n = c], j ascending in short8
    const float* wk = Wc + (size_t)h * (2 * D_ * D_) + D_ * D_;
    short8 bfrag[4][2];
    #pragma unroll
    for (int t = 0; t < 4; ++t) {
        const int d = t * 16 + c;
        #pragma unroll
        for (int half = 0; half < 2; ++half) {
            uint4v f;
            #pragma unroll
            for (int j2 = 0; j2 < 4; ++j2) {
                const int e = half * 32 + q * 8 + 2 * j2;
                f[j2] = pack_bf16(wk[(size_t)e * D_ + d], wk[(size_t)(e + 1) * D_ + d]);
            }
            bfrag[t][half] = __builtin_bit_cast(short8, f);
        }
    }

    float qbl[4], wol[4];
    #pragma unroll
    for (int t = 0; t < 4; ++t) {
        qbl[t] = s_qb[t * 16 + c];
        wol[t] = s_wo[t * 16 + c];
    }

    const float* Kb = K + (size_t)bh * KLEN_ * D_ + (size_t)split * ROWS_PER_BLOCK * D_;
    float*       ob = out + (size_t)bh * KLEN_ + (size_t)split * ROWS_PER_BLOCK;
    unsigned char* myTile = s_tile[wave];

    // wave's tile t covers rows (t*WAVES + wave)*16 .. +15
    // staging load j (coalesced 1 KB/wave): lane gets row j*4 + q, f32 cols c*4..c*4+3
    #define TILE_PTR(t) (Kb + (size_t)(((t) * WAVES + wave) * 16) * D_)

    float4v st[2][4];
    #pragma unroll
    for (int j = 0; j < 4; ++j)
        st[0][j] = *(const float4v*)(TILE_PTR(0) + j * 256 + lane * 4);

    for (int t = 0; t < TILES; ++t) {
        const int cb = t & 1, nb = cb ^ 1;
        if (t + 1 < TILES) {
            #pragma unroll
            for (int j = 0; j < 4; ++j)
                st[nb][j] = *(const float4v*)(TILE_PTR(t + 1) + j * 256 + lane * 4);
        }

        // pack f32 -> bf16 pairs, write 8 B/lane/row-group (conflict-free phases)
        #pragma unroll
        for (int j = 0; j < 4; ++j) {
            const int r = j * 4 + q;
            uint2v w;
            w[0] = pack_bf16(st[cb][j][0], st[cb][j][1]);
            w[1] = pack_bf16(st[cb][j][2], st[cb][j][3]);
            *(uint2v*)(myTile + r * LDS_ROW + c * 8) = w;
        }

        // A fragments: lane (c,q) reads row c, bf16 elems q*8..+7 (+32 for af1)
        short8 af0 = *(const short8*)(myTile + c * LDS_ROW + q * 16);
        short8 af1 = *(const short8*)(myTile + c * LDS_ROW + 64 + q * 16);

        float4v pr = {0.f, 0.f, 0.f, 0.f};
        #pragma unroll
        for (int tt = 0; tt < 4; ++tt) {
            float4v acc = {0.f, 0.f, 0.f, 0.f};
            acc = __builtin_amdgcn_mfma_f32_16x16x32_bf16(af0, bfrag[tt][0], acc, 0, 0, 0);
            acc = __builtin_amdgcn_mfma_f32_16x16x32_bf16(af1, bfrag[tt][1], acc, 0, 0, 0);
            #pragma unroll
            for (int r = 0; r < 4; ++r) {
                float hv = fmaxf(acc[r] + qbl[tt], 0.f);  // C/D: col=c, row=q*4+r
                pr[r] += hv * wol[tt];
            }
        }

        // reduce over the 16 d-columns (xor within c-nibble), store 16 rows
        const int krow = (t * WAVES + wave) * 16;
        #pragma unroll
        for (int r = 0; r < 4; ++r) {
            float v = pr[r];
            v += __shfl_xor(v, 1);
            v += __shfl_xor(v, 2);
            v += __shfl_xor(v, 4);
            v += __shfl_xor(v, 8);
            if (c == r) ob[krow + q * 4 + r] = v;
        }
    }
    #undef TILE_PTR
}

extern "C" void kernel_launch(void* const* d_in, const int* in_sizes, int n_in,
                              void* d_out, int out_size, void* d_ws, size_t ws_size,
                              hipStream_t stream) {
    const float* Q    = (const float*)d_in[0];
    const float* K    = (const float*)d_in[1];
    const float* Wc   = (const float*)d_in[2];
    const float* Wo   = (const float*)d_in[3];
    const float* bias = (const float*)d_in[4];
    float* out = (float*)d_out;

    dim3 grid(B_ * H_ * SPLIT);  // 4096 blocks
    dim3 block(256);
    nais_score_kernel<<<grid, block, 0, stream>>>(Q, K, Wc, Wo, bias, out);
}